// Round 9
// baseline (156.098 us; speedup 1.0000x reference)
//
#include <hip/hip_runtime.h>
#include <hip/hip_bf16.h>

// 3D bilateral filter, radius 2 (125 taps), input (2,1,128,128,128) f32.
// v9: all-f16 data path via v_fma_mix_f32. Evidence: v7/v8 showed per-tap
// cost dominated by pk_f32 ops (4 cyc, 128 f32 lanes structural) and LDS
// traffic; cvt was never slow (v8 falsified that). This round removes ALL
// f32 packed ops and the f32 tile:
//  - single f16 LDS tile (5.8 KB), values scaled by sR, sentinel clamped to
//    60000 (finite in f16; t^2 ~ 3.5e9 -> y << 0 -> w=+0 == OOB mask).
//  - t = v_pk_add_f16 (2 taps, 2 cyc)
//  - y = v_fma_mix_f32(t, -t, CC) per tap (full-rate mixed f16*f16+f32)
//  - y = max(y, 2^23): low 16 bits of y == f16 encoding of the weight
//    (v8-verified mantissa magic; BASE16 = 2^23 + 15*1024)
//  - num/den accumulate in f32 via v_fma_mix_f32 (w = f16 lo of y, x = f16
//    lane of tap word, 1.0 inline for den). No perms, no f16 accum error.
// 9 insts / 18 cyc per 2 taps, all full-rate. 2x ds_read_b64 per row.

#define RADIUS 2
#define N 128
#define TX 16
#define TY 8
#define TZ 8
#define PITCH (TX + 2 * RADIUS)      // 20 elements per row
#define LYD (TY + 2 * RADIUS)        // 12
#define LZD (TZ + 2 * RADIUS)        // 12
#define LDS_SIZE (PITCH * LYD * LZD) // 2880 elements (f16 -> 5760 B)

#define LOG2E 1.4426950408889634f
#define BIG 1.0e18f
#define MAGIC 8388608.0f             // 2^23
#define BASE16 8403968.0f            // 2^23 + 15*1024 (f16 bias << 10)
#define SENT 60000.0f                // sentinel clamp (finite in f16)

__global__ __launch_bounds__(256, 6) void bilateral3d_kernel(
    const float* __restrict__ in, const float* __restrict__ p_sx,
    const float* __restrict__ p_sy, const float* __restrict__ p_sz,
    const float* __restrict__ p_cs, float* __restrict__ out) {
  __shared__ _Float16 h[LDS_SIZE];

  const int tid = threadIdx.x;
  const int x0 = blockIdx.x * TX;
  const int y0 = blockIdx.y * TY;
  const int zb = blockIdx.z;  // low 4 bits = z-tile, bit 4 = batch
  const int z0 = (zb & 15) * TZ;
  const int b = zb >> 4;

  const float sxv = p_sx[0], syv = p_sy[0], szv = p_sz[0], csv = p_cs[0];
  const float K10 = 1024.0f * LOG2E;  // log2 -> f16-exponent-units scale
  const float AX2 = K10 / (2.0f * sxv * sxv);
  const float AY2 = K10 / (2.0f * syv * syv);
  const float AZ2 = K10 / (2.0f * szv * szv);
  const float AX2_4 = 4.0f * AX2;
  const float sR = __builtin_sqrtf(K10 / (2.0f * csv * csv));  // range scale

  const float* vol = in + (size_t)b * (N * N * N);

  // --- stage scaled, clamped f16 tile (OOB -> finite sentinel) ---
  for (int i = tid; i < LDS_SIZE; i += 256) {
    int lx = i % PITCH;
    int t = i / PITCH;
    int ly = t % LYD;
    int lz = t / LYD;
    int gx = x0 + lx - RADIUS;
    int gy = y0 + ly - RADIUS;
    int gz = z0 + lz - RADIUS;
    float v = BIG;
    if ((unsigned)gx < N && (unsigned)gy < N && (unsigned)gz < N)
      v = vol[((size_t)gz * N + gy) * N + gx];
    h[i] = (_Float16)__builtin_fminf(v * sR, SENT);
  }
  __syncthreads();

  const int tx = tid & 3;         // x-group: voxels x0+4tx .. x0+4tx+3
  const int ty = (tid >> 2) & 7;
  const int tz = tid >> 5;

  const int xw = 4 * tx;  // element offset of this thread's 8-elem tap window
  const unsigned* hw = (const unsigned*)h;  // f16-pair words

  // center row words: cw1 = {f2,f3} = {xs0,xs1}, cw2 = {f4,f5} = {xs2,xs3}
  const int cbase = ((tz + RADIUS) * LYD + (ty + RADIUS)) * PITCH + xw;
  const unsigned cw1 = hw[(cbase >> 1) + 1];
  const unsigned cw2 = hw[(cbase >> 1) + 2];
  // broadcast pairs {xs_v, xs_v}
  const unsigned XS0 = __builtin_amdgcn_perm(cw1, cw1, 0x01000100);
  const unsigned XS1 = __builtin_amdgcn_perm(cw1, cw1, 0x03020302);
  const unsigned XS2 = __builtin_amdgcn_perm(cw2, cw2, 0x01000100);
  const unsigned XS3 = __builtin_amdgcn_perm(cw2, cw2, 0x03020302);

  float n0 = 0, n1 = 0, n2 = 0, n3 = 0;
  float e0 = 0, e1 = 0, e2 = 0, e3 = 0;

  // 2 taps of one voxel: GW = f16 pair, CL/CH = f32 constants per lane
#define PKMIX(XS, GW, CL, CH, NN, DD)                                       \
  {                                                                         \
    unsigned _t;                                                            \
    asm("v_pk_add_f16 %0, %1, %2 neg_lo:[0,1] neg_hi:[0,1]"                 \
        : "=v"(_t) : "v"(XS), "v"(GW));                                     \
    float _yl, _yh;                                                         \
    asm("v_fma_mix_f32 %0, %1, -%1, %2 op_sel_hi:[1,1,0]"                   \
        : "=v"(_yl) : "v"(_t), "v"(CL));                                    \
    asm("v_fma_mix_f32 %0, %1, -%1, %2 op_sel:[1,1,0] op_sel_hi:[1,1,0]"    \
        : "=v"(_yh) : "v"(_t), "v"(CH));                                    \
    _yl = __builtin_fmaxf(_yl, MAGIC);                                      \
    _yh = __builtin_fmaxf(_yh, MAGIC);                                      \
    asm("v_fma_mix_f32 %0, %1, %2, %0 op_sel_hi:[1,1,0]"                    \
        : "+v"(NN) : "v"(_yl), "v"(GW));                                    \
    asm("v_fma_mix_f32 %0, %1, %2, %0 op_sel:[0,1,0] op_sel_hi:[1,1,0]"     \
        : "+v"(NN) : "v"(_yh), "v"(GW));                                    \
    asm("v_fma_mix_f32 %0, %1, 1.0, %0 op_sel_hi:[1,0,0]"                   \
        : "+v"(DD) : "v"(_yl));                                             \
    asm("v_fma_mix_f32 %0, %1, 1.0, %0 op_sel_hi:[1,0,0]"                   \
        : "+v"(DD) : "v"(_yh));                                             \
  }

  // leftover |dx|=2 taps for two voxels a (lo lane) and b (hi lane):
  // XSab = {xsa, xsb}, GP = {ga, gb} (pre-permed), same CC both lanes
#define SC2MIX(XSAB, GP, CC, NA, DA, NB, DB)                                \
  {                                                                         \
    unsigned _t;                                                            \
    asm("v_pk_add_f16 %0, %1, %2 neg_lo:[0,1] neg_hi:[0,1]"                 \
        : "=v"(_t) : "v"(XSAB), "v"(GP));                                   \
    float _yl, _yh;                                                         \
    asm("v_fma_mix_f32 %0, %1, -%1, %2 op_sel_hi:[1,1,0]"                   \
        : "=v"(_yl) : "v"(_t), "v"(CC));                                    \
    asm("v_fma_mix_f32 %0, %1, -%1, %2 op_sel:[1,1,0] op_sel_hi:[1,1,0]"    \
        : "=v"(_yh) : "v"(_t), "v"(CC));                                    \
    _yl = __builtin_fmaxf(_yl, MAGIC);                                      \
    _yh = __builtin_fmaxf(_yh, MAGIC);                                      \
    asm("v_fma_mix_f32 %0, %1, %2, %0 op_sel_hi:[1,1,0]"                    \
        : "+v"(NA) : "v"(_yl), "v"(GP));                                    \
    asm("v_fma_mix_f32 %0, %1, %2, %0 op_sel:[0,1,0] op_sel_hi:[1,1,0]"     \
        : "+v"(NB) : "v"(_yh), "v"(GP));                                    \
    asm("v_fma_mix_f32 %0, %1, 1.0, %0 op_sel_hi:[1,0,0]"                   \
        : "+v"(DA) : "v"(_yl));                                             \
    asm("v_fma_mix_f32 %0, %1, 1.0, %0 op_sel_hi:[1,0,0]"                   \
        : "+v"(DB) : "v"(_yh));                                             \
  }

#pragma unroll 1
  for (int dz = -RADIUS; dz <= RADIUS; ++dz) {
    const float pz2 = AZ2 * (float)(dz * dz);
    const int zrow = (tz + RADIUS + dz) * LYD;
#pragma unroll
    for (int dy = -RADIUS; dy <= RADIUS; ++dy) {
      const float cc0 = BASE16 - (pz2 + AY2 * (float)(dy * dy));
      const float cm1 = cc0 - AX2;
      const float cm4 = cc0 - AX2_4;

      const int rb = (zrow + (ty + RADIUS + dy)) * PITCH + xw;
      const int rb2 = rb >> 1;  // even -> 8B-aligned word index
      const uint2 Wa = *(const uint2*)&hw[rb2];      // w0={f0,f1}, w1={f2,f3}
      const uint2 Wb = *(const uint2*)&hw[rb2 + 2];  // w2={f4,f5}, w3={f6,f7}
      const unsigned w0 = Wa.x, w1 = Wa.y, w2 = Wb.x, w3 = Wb.y;

      // voxel 0 (center f2): w0 -> dx(-2,-1), w1 -> dx(0,+1)
      PKMIX(XS0, w0, cm4, cm1, n0, e0)
      PKMIX(XS0, w1, cc0, cm1, n0, e0)
      // voxel 1 (center f3): w1 -> dx(-1,0), w2 -> dx(+1,+2)
      PKMIX(XS1, w1, cm1, cc0, n1, e1)
      PKMIX(XS1, w2, cm1, cm4, n1, e1)
      // voxel 2 (center f4): w1 -> dx(-2,-1), w2 -> dx(0,+1)
      PKMIX(XS2, w1, cm4, cm1, n2, e2)
      PKMIX(XS2, w2, cc0, cm1, n2, e2)
      // voxel 3 (center f5): w2 -> dx(-1,0), w3 -> dx(+1,+2)
      PKMIX(XS3, w2, cm1, cc0, n3, e3)
      PKMIX(XS3, w3, cm1, cm4, n3, e3)

      // leftovers (|dx|=2): v0 taps f4 (w2.lo), v1 taps f1 (w0.hi)
      {
        const unsigned GP = __builtin_amdgcn_perm(w0, w2, 0x07060100);
        SC2MIX(cw1, GP, cm4, n0, e0, n1, e1)
      }
      // v2 taps f6 (w3.lo), v3 taps f3 (w1.hi)
      {
        const unsigned GP = __builtin_amdgcn_perm(w1, w3, 0x07060100);
        SC2MIX(cw2, GP, cm4, n2, e2, n3, e3)
      }
    }
  }

  float4 r;
  r.x = n0 / (e0 * sR);
  r.y = n1 / (e1 * sR);
  r.z = n2 / (e2 * sR);
  r.w = n3 / (e3 * sR);

  const int gz = z0 + tz, gy = y0 + ty;
  *(float4*)&out[(((size_t)b * N + gz) * N + gy) * N + (x0 + xw)] = r;
}

extern "C" void kernel_launch(void* const* d_in, const int* in_sizes, int n_in,
                              void* d_out, int out_size, void* d_ws, size_t ws_size,
                              hipStream_t stream) {
  const float* in = (const float*)d_in[0];
  const float* sx = (const float*)d_in[1];
  const float* sy = (const float*)d_in[2];
  const float* sz = (const float*)d_in[3];
  const float* cs = (const float*)d_in[4];
  float* out = (float*)d_out;

  dim3 grid(N / TX, N / TY, (N / TZ) * 2);  // 8 x 16 x 32
  bilateral3d_kernel<<<grid, 256, 0, stream>>>(in, sx, sy, sz, cs, out);
}

// Round 10
// 138.986 us; speedup vs baseline: 1.1231x; 1.1231x over previous
//
#include <hip/hip_runtime.h>
#include <hip/hip_bf16.h>

// 3D bilateral filter, radius 2 (125 taps), input (2,1,128,128,128) f32.
// v10: all-scalar taps. Unified cost model fitted across v5/v7/v9:
// sustained clock ~1.6 GHz under VALU load; ALL VOP3P (pk_f32/pk_f16/fma_mix)
// are 4 cyc/wave64; scalar f32 VALU and v_cvt_u32_f32 are 2 cyc. So packed
// math never bought throughput — the cheapest tap is scalar:
//   t = xs - fs                      (v_sub, 2 cyc)
//   f = fma(t, -t, CC)               (v_fma w/ neg modifier, 2 cyc)
//   q = sat_u32(f)                   (v_cvt_u32_f32, 2 cyc; OOB/far -> 0)
//   den += asfloat(q)                (v_add, 2)
//   num = fma(w, fs, num)            (v_fma, 2)        => 10 cyc/tap
// Tile pre-scaled by sR at staging (no per-row scaling muls; epilogue
// divides den by sR once). Sentinel: (1e18*sR)^2 -> -inf -> w=+0 == mask.
// Shell: v5's 16x8x8 tile, 4 voxels/thread, 8 acc chains, dy unrolled,
// lb(256,8) for 8 waves/SIMD latency hiding.

#define RADIUS 2
#define N 128
#define TX 16
#define TY 8
#define TZ 8
#define PITCH (TX + 2 * RADIUS)      // 20 floats per row (16B-aligned rows)
#define LYD (TY + 2 * RADIUS)        // 12
#define LZD (TZ + 2 * RADIUS)        // 12
#define LDS_SIZE (PITCH * LYD * LZD) // 2880 floats = 11.25 KB

#define LOG2E 1.4426950408889634f
#define BIG 1.0e18f
#define EXP2_SCALE 8388608.0f        // 2^23
#define EXP2_BIAS 1065353216.0f      // 127 * 2^23

__global__ __launch_bounds__(256, 8) void bilateral3d_kernel(
    const float* __restrict__ in, const float* __restrict__ p_sx,
    const float* __restrict__ p_sy, const float* __restrict__ p_sz,
    const float* __restrict__ p_cs, float* __restrict__ out) {
  __shared__ float s[LDS_SIZE];

  const int tid = threadIdx.x;
  const int x0 = blockIdx.x * TX;
  const int y0 = blockIdx.y * TY;
  const int zb = blockIdx.z;  // low 4 bits = z-tile, bit 4 = batch
  const int z0 = (zb & 15) * TZ;
  const int b = zb >> 4;

  const float sxv = p_sx[0], syv = p_sy[0], szv = p_sz[0], csv = p_cs[0];
  const float AX2 = EXP2_SCALE * LOG2E / (2.0f * sxv * sxv);
  const float AY2 = EXP2_SCALE * LOG2E / (2.0f * syv * syv);
  const float AZ2 = EXP2_SCALE * LOG2E / (2.0f * szv * szv);
  const float AX2_4 = 4.0f * AX2;
  const float sR = __builtin_sqrtf(EXP2_SCALE * LOG2E / (2.0f * csv * csv));

  const float* vol = in + (size_t)b * (N * N * N);

  // --- stage 20x12x12 halo tile, PRE-SCALED by sR (OOB -> sentinel) ---
  for (int i = tid; i < LDS_SIZE; i += 256) {
    int lx = i % PITCH;
    int t = i / PITCH;
    int ly = t % LYD;
    int lz = t / LYD;
    int gx = x0 + lx - RADIUS;
    int gy = y0 + ly - RADIUS;
    int gz = z0 + lz - RADIUS;
    float v = BIG;
    if ((unsigned)gx < N && (unsigned)gy < N && (unsigned)gz < N)
      v = vol[((size_t)gz * N + gy) * N + gx];
    s[i] = v * sR;
  }
  __syncthreads();

  const int tx = tid & 3;         // x-group: voxels x0+4tx .. x0+4tx+3
  const int ty = (tid >> 2) & 7;
  const int tz = tid >> 5;

  const int xw = 4 * tx;  // word offset within row of this thread's tap window

  // centers (scaled): words [xw+2 .. xw+5] of the (dz=0,dy=0) row
  const int cbase = ((tz + RADIUS) * LYD + (ty + RADIUS)) * PITCH + xw;
  const float4 CA = *(const float4*)&s[cbase];
  const float4 CB = *(const float4*)&s[cbase + 4];
  const float xc0 = CA.z, xc1 = CA.w, xc2 = CB.x, xc3 = CB.y;

  float n0 = 0, n1 = 0, n2 = 0, n3 = 0;
  float e0 = 0, e1 = 0, e2 = 0, e3 = 0;  // denominators

  // scalar Schraudolph tap: 5 insts / 10 cyc
#define TAP(XC, FV, CC, NN, DD)                          \
  {                                                      \
    float _t = (XC) - (FV);                              \
    float _f = fmaf(_t, -_t, (CC));                      \
    unsigned _q;                                         \
    asm("v_cvt_u32_f32 %0, %1" : "=v"(_q) : "v"(_f));    \
    float _w = __uint_as_float(_q);                      \
    DD += _w;                                            \
    NN = fmaf(_w, (FV), NN);                             \
  }

#pragma unroll 1
  for (int dz = -RADIUS; dz <= RADIUS; ++dz) {
    const float pz2 = AZ2 * (float)(dz * dz);
    const int zrow = (tz + RADIUS + dz) * LYD;
#pragma unroll
    for (int dy = -RADIUS; dy <= RADIUS; ++dy) {
      const float cc0 = EXP2_BIAS - (pz2 + AY2 * (float)(dy * dy));
      const float cm1 = cc0 - AX2;    // |dx| = 1
      const float cm4 = cc0 - AX2_4;  // |dx| = 2
      const int rb = (zrow + (ty + RADIUS + dy)) * PITCH + xw;
      const float4 A = *(const float4*)&s[rb];
      const float4 B = *(const float4*)&s[rb + 4];
      const float f0 = A.x, f1 = A.y, f2 = A.z, f3 = A.w;
      const float f4 = B.x, f5 = B.y, f6 = B.z, f7 = B.w;

      // dx = -2
      TAP(xc0, f0, cm4, n0, e0)
      TAP(xc1, f1, cm4, n1, e1)
      TAP(xc2, f2, cm4, n2, e2)
      TAP(xc3, f3, cm4, n3, e3)
      // dx = -1
      TAP(xc0, f1, cm1, n0, e0)
      TAP(xc1, f2, cm1, n1, e1)
      TAP(xc2, f3, cm1, n2, e2)
      TAP(xc3, f4, cm1, n3, e3)
      // dx = 0
      TAP(xc0, f2, cc0, n0, e0)
      TAP(xc1, f3, cc0, n1, e1)
      TAP(xc2, f4, cc0, n2, e2)
      TAP(xc3, f5, cc0, n3, e3)
      // dx = +1
      TAP(xc0, f3, cm1, n0, e0)
      TAP(xc1, f4, cm1, n1, e1)
      TAP(xc2, f5, cm1, n2, e2)
      TAP(xc3, f6, cm1, n3, e3)
      // dx = +2
      TAP(xc0, f4, cm4, n0, e0)
      TAP(xc1, f5, cm4, n1, e1)
      TAP(xc2, f6, cm4, n2, e2)
      TAP(xc3, f7, cm4, n3, e3)
    }
  }

  // values were pre-scaled by sR: out = (num/sR-units) / (den * sR)
  float4 r;
  r.x = n0 / (e0 * sR);
  r.y = n1 / (e1 * sR);
  r.z = n2 / (e2 * sR);
  r.w = n3 / (e3 * sR);

  const int gz = z0 + tz, gy = y0 + ty;
  *(float4*)&out[(((size_t)b * N + gz) * N + gy) * N + (x0 + xw)] = r;
}

extern "C" void kernel_launch(void* const* d_in, const int* in_sizes, int n_in,
                              void* d_out, int out_size, void* d_ws, size_t ws_size,
                              hipStream_t stream) {
  const float* in = (const float*)d_in[0];
  const float* sx = (const float*)d_in[1];
  const float* sy = (const float*)d_in[2];
  const float* sz = (const float*)d_in[3];
  const float* cs = (const float*)d_in[4];
  float* out = (float*)d_out;

  dim3 grid(N / TX, N / TY, (N / TZ) * 2);  // 8 x 16 x 32
  bilateral3d_kernel<<<grid, 256, 0, stream>>>(in, sx, sy, sz, cs, out);
}

// Round 11
// 136.665 us; speedup vs baseline: 1.1422x; 1.0170x over previous
//
#include <hip/hip_runtime.h>
#include <hip/hip_bf16.h>

// 3D bilateral filter, radius 2 (125 taps), input (2,1,128,128,128) f32.
// v11: v10 with the spills removed. v10's lb(256,8) capped VGPRs at 32 ->
// ~28 MB scratch round-trip (WRITE_SIZE 16->45 MB in rocprof). lb(256,4)
// is the v3-verified no-spill configuration (VGPR ~36) for this shell.
// Tap: 5 scalar insts (sub, fma(t,-t,CC), saturating v_cvt_u32_f32,
// add, fma). Tile pre-scaled by sR at staging; epilogue divides den by sR.
// OOB: sentinel 1e18*sR -> t^2 overflow -> -inf -> cvt saturates to 0 ->
// w=+0 exactly == reference validity mask.

#define RADIUS 2
#define N 128
#define TX 16
#define TY 8
#define TZ 8
#define PITCH (TX + 2 * RADIUS)      // 20 floats per row (16B-aligned rows)
#define LYD (TY + 2 * RADIUS)        // 12
#define LZD (TZ + 2 * RADIUS)        // 12
#define LDS_SIZE (PITCH * LYD * LZD) // 2880 floats = 11.25 KB

#define LOG2E 1.4426950408889634f
#define BIG 1.0e18f
#define EXP2_SCALE 8388608.0f        // 2^23
#define EXP2_BIAS 1065353216.0f      // 127 * 2^23

__global__ __launch_bounds__(256, 4) void bilateral3d_kernel(
    const float* __restrict__ in, const float* __restrict__ p_sx,
    const float* __restrict__ p_sy, const float* __restrict__ p_sz,
    const float* __restrict__ p_cs, float* __restrict__ out) {
  __shared__ float s[LDS_SIZE];

  const int tid = threadIdx.x;
  const int x0 = blockIdx.x * TX;
  const int y0 = blockIdx.y * TY;
  const int zb = blockIdx.z;  // low 4 bits = z-tile, bit 4 = batch
  const int z0 = (zb & 15) * TZ;
  const int b = zb >> 4;

  const float sxv = p_sx[0], syv = p_sy[0], szv = p_sz[0], csv = p_cs[0];
  const float AX2 = EXP2_SCALE * LOG2E / (2.0f * sxv * sxv);
  const float AY2 = EXP2_SCALE * LOG2E / (2.0f * syv * syv);
  const float AZ2 = EXP2_SCALE * LOG2E / (2.0f * szv * szv);
  const float AX2_4 = 4.0f * AX2;
  const float sR = __builtin_sqrtf(EXP2_SCALE * LOG2E / (2.0f * csv * csv));

  const float* vol = in + (size_t)b * (N * N * N);

  // --- stage 20x12x12 halo tile, PRE-SCALED by sR (OOB -> sentinel) ---
  for (int i = tid; i < LDS_SIZE; i += 256) {
    int lx = i % PITCH;
    int t = i / PITCH;
    int ly = t % LYD;
    int lz = t / LYD;
    int gx = x0 + lx - RADIUS;
    int gy = y0 + ly - RADIUS;
    int gz = z0 + lz - RADIUS;
    float v = BIG;
    if ((unsigned)gx < N && (unsigned)gy < N && (unsigned)gz < N)
      v = vol[((size_t)gz * N + gy) * N + gx];
    s[i] = v * sR;
  }
  __syncthreads();

  const int tx = tid & 3;         // x-group: voxels x0+4tx .. x0+4tx+3
  const int ty = (tid >> 2) & 7;
  const int tz = tid >> 5;

  const int xw = 4 * tx;  // word offset within row of this thread's tap window

  // centers (scaled): words [xw+2 .. xw+5] of the (dz=0,dy=0) row
  const int cbase = ((tz + RADIUS) * LYD + (ty + RADIUS)) * PITCH + xw;
  const float4 CA = *(const float4*)&s[cbase];
  const float4 CB = *(const float4*)&s[cbase + 4];
  const float xc0 = CA.z, xc1 = CA.w, xc2 = CB.x, xc3 = CB.y;

  float n0 = 0, n1 = 0, n2 = 0, n3 = 0;
  float e0 = 0, e1 = 0, e2 = 0, e3 = 0;  // denominators

  // scalar Schraudolph tap: 5 insts / 10 cyc
#define TAP(XC, FV, CC, NN, DD)                          \
  {                                                      \
    float _t = (XC) - (FV);                              \
    float _f = fmaf(_t, -_t, (CC));                      \
    unsigned _q;                                         \
    asm("v_cvt_u32_f32 %0, %1" : "=v"(_q) : "v"(_f));    \
    float _w = __uint_as_float(_q);                      \
    DD += _w;                                            \
    NN = fmaf(_w, (FV), NN);                             \
  }

#pragma unroll 1
  for (int dz = -RADIUS; dz <= RADIUS; ++dz) {
    const float pz2 = AZ2 * (float)(dz * dz);
    const int zrow = (tz + RADIUS + dz) * LYD;
#pragma unroll
    for (int dy = -RADIUS; dy <= RADIUS; ++dy) {
      const float cc0 = EXP2_BIAS - (pz2 + AY2 * (float)(dy * dy));
      const float cm1 = cc0 - AX2;    // |dx| = 1
      const float cm4 = cc0 - AX2_4;  // |dx| = 2
      const int rb = (zrow + (ty + RADIUS + dy)) * PITCH + xw;
      const float4 A = *(const float4*)&s[rb];
      const float4 B = *(const float4*)&s[rb + 4];
      const float f0 = A.x, f1 = A.y, f2 = A.z, f3 = A.w;
      const float f4 = B.x, f5 = B.y, f6 = B.z, f7 = B.w;

      // dx = -2
      TAP(xc0, f0, cm4, n0, e0)
      TAP(xc1, f1, cm4, n1, e1)
      TAP(xc2, f2, cm4, n2, e2)
      TAP(xc3, f3, cm4, n3, e3)
      // dx = -1
      TAP(xc0, f1, cm1, n0, e0)
      TAP(xc1, f2, cm1, n1, e1)
      TAP(xc2, f3, cm1, n2, e2)
      TAP(xc3, f4, cm1, n3, e3)
      // dx = 0
      TAP(xc0, f2, cc0, n0, e0)
      TAP(xc1, f3, cc0, n1, e1)
      TAP(xc2, f4, cc0, n2, e2)
      TAP(xc3, f5, cc0, n3, e3)
      // dx = +1
      TAP(xc0, f3, cm1, n0, e0)
      TAP(xc1, f4, cm1, n1, e1)
      TAP(xc2, f5, cm1, n2, e2)
      TAP(xc3, f6, cm1, n3, e3)
      // dx = +2
      TAP(xc0, f4, cm4, n0, e0)
      TAP(xc1, f5, cm4, n1, e1)
      TAP(xc2, f6, cm4, n2, e2)
      TAP(xc3, f7, cm4, n3, e3)
    }
  }

  // values were pre-scaled by sR: out = num / (den * sR)
  float4 r;
  r.x = n0 / (e0 * sR);
  r.y = n1 / (e1 * sR);
  r.z = n2 / (e2 * sR);
  r.w = n3 / (e3 * sR);

  const int gz = z0 + tz, gy = y0 + ty;
  *(float4*)&out[(((size_t)b * N + gz) * N + gy) * N + (x0 + xw)] = r;
}

extern "C" void kernel_launch(void* const* d_in, const int* in_sizes, int n_in,
                              void* d_out, int out_size, void* d_ws, size_t ws_size,
                              hipStream_t stream) {
  const float* in = (const float*)d_in[0];
  const float* sx = (const float*)d_in[1];
  const float* sy = (const float*)d_in[2];
  const float* sz = (const float*)d_in[3];
  const float* cs = (const float*)d_in[4];
  float* out = (float*)d_out;

  dim3 grid(N / TX, N / TY, (N / TZ) * 2);  // 8 x 16 x 32
  bilateral3d_kernel<<<grid, 256, 0, stream>>>(in, sx, sy, sz, cs, out);
}